// Round 8
// baseline (351.973 us; speedup 1.0000x reference)
//
#include <hip/hip_runtime.h>
#include <stdint.h>

#define ISZ 10
#define HSZ 20
#define BSZ 4096
#define TSZ 512
#define CPW 6                          // chains (batches) per wave: 3 groups x ILP 2
#define NBLK ((BSZ + CPW - 1) / CPW)   // 683 one-wave blocks -> ~1 wave/SIMD

typedef __fp16 half2_t __attribute__((ext_vector_type(2)));

__device__ __forceinline__ float fdot2(half2_t a, half2_t b, float c) {
    return __builtin_amdgcn_fdot2(a, b, c, false);
}

__global__ __launch_bounds__(64, 2) void lstm_fwd(
    const float* __restrict__ data, const float* __restrict__ Wih,
    const float* __restrict__ Whh, const float* __restrict__ bih,
    const float* __restrict__ bhh, float* __restrict__ partials)
{
    // Two independent LSTM chains (A,B) per wave, interleaved in one
    // instruction stream: chain B issues inside chain A's latency stalls
    // (co-resident waves phase-lock and don't do this; in-wave ILP does).
    // h-exchange in registers via ds_bpermute on raw f32 (no LDS buffer).
    const int lane  = threadIdx.x;        // 0..63
    const int g     = lane / HSZ;         // batch group 0..3 (3 = idle lanes)
    const int j     = lane - g * HSZ;     // hidden unit 0..19
    const int batchA = blockIdx.x * CPW + g;
    const int batchB = blockIdx.x * CPW + 3 + g;
    const bool activeA = (g < 3) && (batchA < BSZ);
    const bool activeB = (g < 3) && (batchB < BSZ);
    const int blA = activeA ? batchA : 0;
    const int blB = activeB ? batchB : 0;

    // Per-thread weight rows, f16-packed, activation scale constants folded:
    // sigmoid gates (i,f,o) scaled by -log2e, tanh gate (g) by +2*log2e.
    // Gate order i,f,g,o -> rows j, j+20, j+40, j+60. Shared by both chains.
    const float sc[4] = {-1.44269504f, -1.44269504f, 2.88539008f, -1.44269504f};
    half2_t wih2[4][ISZ / 2], whh2[4][HSZ / 2];
    float bias[4];
#pragma unroll
    for (int q = 0; q < 4; ++q) {
        const int row = q * HSZ + j;
#pragma unroll
        for (int i = 0; i < ISZ / 2; ++i) {
            wih2[q][i].x = (__fp16)(sc[q] * Wih[row * ISZ + 2 * i]);
            wih2[q][i].y = (__fp16)(sc[q] * Wih[row * ISZ + 2 * i + 1]);
        }
#pragma unroll
        for (int k = 0; k < HSZ / 2; ++k) {
            whh2[q][k].x = (__fp16)(sc[q] * Whh[row * HSZ + 2 * k]);
            whh2[q][k].y = (__fp16)(sc[q] * Whh[row * HSZ + 2 * k + 1]);
        }
        bias[q] = sc[q] * (bih[row] + bhh[row]);
    }

    // bpermute base byte-address of my group's lane 0 (lane index *4).
    // Constant +8k / +8k+4 folds into the ds_bpermute offset field.
    const int gbase = g * HSZ * 4;

    half2_t h2A[HSZ / 2], h2B[HSZ / 2];
#pragma unroll
    for (int k = 0; k < HSZ / 2; ++k) {
        h2A[k] = (half2_t)(__fp16)0.f;
        h2B[k] = (half2_t)(__fp16)0.f;
    }

    float cA = 0.0f, cB = 0.0f, sumA = 0.0f, sumB = 0.0f;
    const float* xbaseA = data + (size_t)blA * (TSZ * ISZ);
    const float* xbaseB = data + (size_t)blB * (TSZ * ISZ);

    half2_t xaA[ISZ / 2], xbA[ISZ / 2], xaB[ISZ / 2], xbB[ISZ / 2];

    auto loadx = [&](half2_t* dst, const float* xb, int t) {
        const float2* p = (const float2*)(xb + t * ISZ);  // 8B-aligned (t*40B)
        float2 v0 = p[0], v1 = p[1], v2 = p[2], v3 = p[3], v4 = p[4];
        dst[0] = __builtin_amdgcn_cvt_pkrtz(v0.x, v0.y);
        dst[1] = __builtin_amdgcn_cvt_pkrtz(v1.x, v1.y);
        dst[2] = __builtin_amdgcn_cvt_pkrtz(v2.x, v2.y);
        dst[3] = __builtin_amdgcn_cvt_pkrtz(v3.x, v3.y);
        dst[4] = __builtin_amdgcn_cvt_pkrtz(v4.x, v4.y);
    };

    auto step2 = [&](const half2_t* xA, const half2_t* xB) {
        float accA[4], accB[4];
        // Interleaved gate dots: independent A/B chains give the scheduler
        // back-to-back issue during each other's dependency stalls.
#pragma unroll
        for (int q = 0; q < 4; ++q) {
            float axA = bias[q], alA = 0.0f, ahA = 0.0f;
            float axB = bias[q], alB = 0.0f, ahB = 0.0f;
#pragma unroll
            for (int i = 0; i < ISZ / 2; ++i) {
                axA = fdot2(wih2[q][i], xA[i], axA);
                axB = fdot2(wih2[q][i], xB[i], axB);
            }
#pragma unroll
            for (int k = 0; k < 5; ++k) {
                alA = fdot2(whh2[q][k], h2A[k], alA);
                alB = fdot2(whh2[q][k], h2B[k], alB);
            }
#pragma unroll
            for (int k = 5; k < 10; ++k) {
                ahA = fdot2(whh2[q][k], h2A[k], ahA);
                ahB = fdot2(whh2[q][k], h2B[k], ahB);
            }
            accA[q] = axA + (alA + ahA);
            accB[q] = axB + (alB + ahB);
        }
        // scales pre-folded: sigmoid = rcp(1+exp2(acc)); tanh = 1-2*rcp(1+exp2(acc))
        float igA = __builtin_amdgcn_rcpf(1.0f + __builtin_amdgcn_exp2f(accA[0]));
        float igB = __builtin_amdgcn_rcpf(1.0f + __builtin_amdgcn_exp2f(accB[0]));
        float fgA = __builtin_amdgcn_rcpf(1.0f + __builtin_amdgcn_exp2f(accA[1]));
        float fgB = __builtin_amdgcn_rcpf(1.0f + __builtin_amdgcn_exp2f(accB[1]));
        float ggA = 1.0f - 2.0f * __builtin_amdgcn_rcpf(1.0f + __builtin_amdgcn_exp2f(accA[2]));
        float ggB = 1.0f - 2.0f * __builtin_amdgcn_rcpf(1.0f + __builtin_amdgcn_exp2f(accB[2]));
        float ogA = __builtin_amdgcn_rcpf(1.0f + __builtin_amdgcn_exp2f(accA[3]));
        float ogB = __builtin_amdgcn_rcpf(1.0f + __builtin_amdgcn_exp2f(accB[3]));
        cA = fgA * cA + igA * ggA;
        cB = fgB * cB + igB * ggB;
        float tcA = 1.0f - 2.0f * __builtin_amdgcn_rcpf(1.0f + __builtin_amdgcn_exp2f(2.88539008f * cA));
        float tcB = 1.0f - 2.0f * __builtin_amdgcn_rcpf(1.0f + __builtin_amdgcn_exp2f(2.88539008f * cB));
        float hnA = ogA * tcA;
        float hnB = ogB * tcB;
        sumA += hnA;
        sumB += hnB;

        // In-register all-gather of the 20 h values per chain: bpermute the
        // raw f32 (starts immediately after hn; no pack on the critical
        // path), then cvt_pkrtz into half2 dot operands. RTZ bias on h is
        // ~2^-12 relative: negligible vs the 2% scalar-sum tolerance.
        int iA = __builtin_bit_cast(int, hnA);
        int iB = __builtin_bit_cast(int, hnB);
#pragma unroll
        for (int k = 0; k < HSZ / 2; ++k) {
            float eA = __builtin_bit_cast(float, __builtin_amdgcn_ds_bpermute(gbase + 8 * k, iA));
            float oA = __builtin_bit_cast(float, __builtin_amdgcn_ds_bpermute(gbase + 8 * k + 4, iA));
            float eB = __builtin_bit_cast(float, __builtin_amdgcn_ds_bpermute(gbase + 8 * k, iB));
            float oB = __builtin_bit_cast(float, __builtin_amdgcn_ds_bpermute(gbase + 8 * k + 4, iB));
            h2A[k] = __builtin_amdgcn_cvt_pkrtz(eA, oA);
            h2B[k] = __builtin_amdgcn_cvt_pkrtz(eB, oB);
        }
    };

    loadx(xaA, xbaseA, 0);
    loadx(xaB, xbaseB, 0);
    for (int t = 0; t < TSZ; t += 2) {
        loadx(xbA, xbaseA, t + 1);        // prefetch: hides under step2(xa*)
        loadx(xbB, xbaseB, t + 1);
        step2(xaA, xaB);
        const int t2 = (t + 2 < TSZ) ? (t + 2) : (TSZ - 1);
        loadx(xaA, xbaseA, t2);           // prefetch next pair
        loadx(xaB, xbaseB, t2);
        step2(xbA, xbB);
    }

    float sum = (activeA ? sumA : 0.0f) + (activeB ? sumB : 0.0f);
#pragma unroll
    for (int off = 32; off > 0; off >>= 1) sum += __shfl_down(sum, off, 64);
    if (lane == 0) partials[blockIdx.x] = sum;
}

__global__ __launch_bounds__(1024) void reduce_partials(
    const float* __restrict__ partials, float* __restrict__ out)
{
    float s = 0.0f;
    for (int i = threadIdx.x; i < NBLK; i += 1024) s += partials[i];
#pragma unroll
    for (int off = 32; off > 0; off >>= 1) s += __shfl_down(s, off, 64);
    __shared__ float wsum[16];
    const int w = threadIdx.x >> 6;
    if ((threadIdx.x & 63) == 0) wsum[w] = s;
    __syncthreads();
    if (threadIdx.x < 16) {
        float v = wsum[threadIdx.x];
#pragma unroll
        for (int off = 8; off > 0; off >>= 1) v += __shfl_down(v, off, 64);
        if (threadIdx.x == 0) out[0] = v;
    }
}

extern "C" void kernel_launch(void* const* d_in, const int* in_sizes, int n_in,
                              void* d_out, int out_size, void* d_ws, size_t ws_size,
                              hipStream_t stream) {
    const float* data = (const float*)d_in[0];
    const float* Wih  = (const float*)d_in[1];
    const float* Whh  = (const float*)d_in[2];
    const float* bih  = (const float*)d_in[3];
    const float* bhh  = (const float*)d_in[4];
    float* out        = (float*)d_out;
    float* partials   = (float*)d_ws;   // NBLK floats, fully written every launch

    lstm_fwd<<<NBLK, 64, 0, stream>>>(data, Wih, Whh, bih, bhh, partials);
    reduce_partials<<<1, 1024, 0, stream>>>(partials, out);
}

// Round 9
// 251.512 us; speedup vs baseline: 1.3994x; 1.3994x over previous
//
#include <hip/hip_runtime.h>
#include <stdint.h>

#define ISZ 10
#define HSZ 20
#define BSZ 4096
#define TSZ 512
#define GPW 6                          // batches (groups) per wave, 10 lanes each
#define NBLK ((BSZ + GPW - 1) / GPW)   // 683 one-wave blocks -> <=1 wave/SIMD

typedef __fp16 half2_t __attribute__((ext_vector_type(2)));

__device__ __forceinline__ float fdot2(half2_t a, half2_t b, float c) {
    return __builtin_amdgcn_fdot2(a, b, c, false);
}

__global__ __launch_bounds__(64, 1) void lstm_fwd(
    const float* __restrict__ data, const float* __restrict__ Wih,
    const float* __restrict__ Whh, const float* __restrict__ bih,
    const float* __restrict__ bhh, float* __restrict__ partials)
{
    // 10 lanes per batch; each lane owns hidden units u0=l and u1=l+10.
    // h-dot columns are paired (k, k+10), so the two per-lane h outputs pack
    // into one half2 with a single LOCAL cvt_pkrtz; the exchange is 10
    // ds_bpermute of pre-paired dwords = ONE LDS-latency leg per step.
    const int lane  = threadIdx.x;        // 0..63
    const int g     = lane / 10;          // batch group 0..5 (6 = idle lanes)
    const int l     = lane - g * 10;      // lane-in-group = unit j
    const int batch = blockIdx.x * GPW + g;
    const bool active = (g < GPW) && (batch < BSZ);
    const int bl = active ? batch : 0;    // clamp for safe loads
    const int gq = (g < GPW) ? g : 0;     // clamp for safe bpermute addrs

    // Weights for 8 gate-rows (2 units x 4 gates), f16-packed, activation
    // scale folded: sigmoid rows (i,f,o) x -log2e, tanh rows (g) x +2log2e.
    // wih pairs: columns (2i, 2i+1). whh pairs: columns (k, k+10)!
    const float sc[4] = {-1.44269504f, -1.44269504f, 2.88539008f, -1.44269504f};
    half2_t wih2[2][4][ISZ / 2], whh2[2][4][ISZ];
    float bias[2][4];
#pragma unroll
    for (int s = 0; s < 2; ++s) {
        const int u = l + 10 * s;
#pragma unroll
        for (int q = 0; q < 4; ++q) {
            const int row = q * HSZ + u;
#pragma unroll
            for (int i = 0; i < ISZ / 2; ++i)
                wih2[s][q][i] = __builtin_amdgcn_cvt_pkrtz(
                    sc[q] * Wih[row * ISZ + 2 * i], sc[q] * Wih[row * ISZ + 2 * i + 1]);
#pragma unroll
            for (int k = 0; k < ISZ; ++k)
                whh2[s][q][k] = __builtin_amdgcn_cvt_pkrtz(
                    sc[q] * Whh[row * HSZ + k], sc[q] * Whh[row * HSZ + k + 10]);
            bias[s][q] = sc[q] * (bih[row] + bhh[row]);
        }
    }

    // h state: h2[k] = (h[k], h[k+10]) replicated in all 10 lanes of the group
    half2_t h2[ISZ];
#pragma unroll
    for (int k = 0; k < ISZ; ++k) h2[k] = (half2_t)(__fp16)0.f;

    float c0 = 0.0f, c1 = 0.0f, sum = 0.0f;
    const float* xbase = data + (size_t)bl * (TSZ * ISZ);

    half2_t xa[ISZ / 2], xb[ISZ / 2];

    auto loadx = [&](half2_t* dst, int t) {
        const float2* p = (const float2*)(xbase + t * ISZ);  // 8B-aligned (t*40B)
        float2 v0 = p[0], v1 = p[1], v2 = p[2], v3 = p[3], v4 = p[4];
        dst[0] = __builtin_amdgcn_cvt_pkrtz(v0.x, v0.y);
        dst[1] = __builtin_amdgcn_cvt_pkrtz(v1.x, v1.y);
        dst[2] = __builtin_amdgcn_cvt_pkrtz(v2.x, v2.y);
        dst[3] = __builtin_amdgcn_cvt_pkrtz(v3.x, v3.y);
        dst[4] = __builtin_amdgcn_cvt_pkrtz(v4.x, v4.y);
    };

    auto step = [&](const half2_t* x) {
        // 8 independent gate-rows, each split into 3 sub-chains (depth <=5):
        // massive in-chain ILP fills trans/exchange latency.
        float acc[2][4];
#pragma unroll
        for (int s = 0; s < 2; ++s)
#pragma unroll
            for (int q = 0; q < 4; ++q) {
                float ax = bias[s][q], al = 0.0f, ah = 0.0f;
#pragma unroll
                for (int i = 0; i < ISZ / 2; ++i) ax = fdot2(wih2[s][q][i], x[i], ax);
#pragma unroll
                for (int k = 0; k < 5; ++k) al = fdot2(whh2[s][q][k], h2[k], al);
#pragma unroll
                for (int k = 5; k < 10; ++k) ah = fdot2(whh2[s][q][k], h2[k], ah);
                acc[s][q] = ax + (al + ah);
            }
        // scales pre-folded: sigmoid = rcp(1+exp2(acc)); tanh = 1-2*rcp(1+exp2(acc))
        float ig0 = __builtin_amdgcn_rcpf(1.0f + __builtin_amdgcn_exp2f(acc[0][0]));
        float ig1 = __builtin_amdgcn_rcpf(1.0f + __builtin_amdgcn_exp2f(acc[1][0]));
        float fg0 = __builtin_amdgcn_rcpf(1.0f + __builtin_amdgcn_exp2f(acc[0][1]));
        float fg1 = __builtin_amdgcn_rcpf(1.0f + __builtin_amdgcn_exp2f(acc[1][1]));
        float gg0 = 1.0f - 2.0f * __builtin_amdgcn_rcpf(1.0f + __builtin_amdgcn_exp2f(acc[0][2]));
        float gg1 = 1.0f - 2.0f * __builtin_amdgcn_rcpf(1.0f + __builtin_amdgcn_exp2f(acc[1][2]));
        float og0 = __builtin_amdgcn_rcpf(1.0f + __builtin_amdgcn_exp2f(acc[0][3]));
        float og1 = __builtin_amdgcn_rcpf(1.0f + __builtin_amdgcn_exp2f(acc[1][3]));
        c0 = fg0 * c0 + ig0 * gg0;
        c1 = fg1 * c1 + ig1 * gg1;
        float tc0 = 1.0f - 2.0f * __builtin_amdgcn_rcpf(1.0f + __builtin_amdgcn_exp2f(2.88539008f * c0));
        float tc1 = 1.0f - 2.0f * __builtin_amdgcn_rcpf(1.0f + __builtin_amdgcn_exp2f(2.88539008f * c1));
        float hn0 = og0 * tc0;   // h[l]
        float hn1 = og1 * tc1;   // h[l+10]
        sum += hn0 + hn1;

        // LOCAL pack (no cross-lane), then one bpermute leg: h2[k] from lane
        // gq*10+k holds (h[k], h[k+10]) — matching the whh pair order.
        half2_t pair = __builtin_amdgcn_cvt_pkrtz(hn0, hn1);
        int pi = __builtin_bit_cast(int, pair);
#pragma unroll
        for (int k = 0; k < ISZ; ++k)
            h2[k] = __builtin_bit_cast(half2_t,
                        __builtin_amdgcn_ds_bpermute((gq * 10 + k) * 4, pi));
    };

    loadx(xa, 0);
    for (int t = 0; t < TSZ; t += 2) {
        loadx(xb, t + 1);                 // prefetch: hides under step(xa)
        step(xa);
        const int t2 = (t + 2 < TSZ) ? (t + 2) : (TSZ - 1);
        loadx(xa, t2);                    // prefetch next pair
        step(xb);
    }

    if (!active) sum = 0.0f;
#pragma unroll
    for (int off = 32; off > 0; off >>= 1) sum += __shfl_down(sum, off, 64);
    if (lane == 0) partials[blockIdx.x] = sum;
}

__global__ __launch_bounds__(1024) void reduce_partials(
    const float* __restrict__ partials, float* __restrict__ out)
{
    float s = 0.0f;
    for (int i = threadIdx.x; i < NBLK; i += 1024) s += partials[i];
#pragma unroll
    for (int off = 32; off > 0; off >>= 1) s += __shfl_down(s, off, 64);
    __shared__ float wsum[16];
    const int w = threadIdx.x >> 6;
    if ((threadIdx.x & 63) == 0) wsum[w] = s;
    __syncthreads();
    if (threadIdx.x < 16) {
        float v = wsum[threadIdx.x];
#pragma unroll
        for (int off = 8; off > 0; off >>= 1) v += __shfl_down(v, off, 64);
        if (threadIdx.x == 0) out[0] = v;
    }
}

extern "C" void kernel_launch(void* const* d_in, const int* in_sizes, int n_in,
                              void* d_out, int out_size, void* d_ws, size_t ws_size,
                              hipStream_t stream) {
    const float* data = (const float*)d_in[0];
    const float* Wih  = (const float*)d_in[1];
    const float* Whh  = (const float*)d_in[2];
    const float* bih  = (const float*)d_in[3];
    const float* bhh  = (const float*)d_in[4];
    float* out        = (float*)d_out;
    float* partials   = (float*)d_ws;   // NBLK floats, fully written every launch

    lstm_fwd<<<NBLK, 64, 0, stream>>>(data, Wih, Whh, bih, bhh, partials);
    reduce_partials<<<1, 1024, 0, stream>>>(partials, out);
}